// Round 2
// baseline (532.359 us; speedup 1.0000x reference)
//
#include <hip/hip_runtime.h>
#include <hip/hip_bf16.h>

#define B_    2
#define S_    2048
#define H_    2048
#define NH_   16
#define NKV_  4
#define D_    128
#define WIN_  1024

typedef __attribute__((ext_vector_type(8))) short short8;
typedef __attribute__((ext_vector_type(4))) float f32x4;

__device__ __forceinline__ void gl2lds16(const void* g, void* l) {
  __builtin_amdgcn_global_load_lds(
      (const __attribute__((address_space(1))) void*)g,
      (__attribute__((address_space(3))) void*)l, 16, 0, 0);
}

__device__ __forceinline__ unsigned short f2bf(float x) {
  union { float f; unsigned int u; } v; v.f = x;
  unsigned int r = v.u + 0x7fffu + ((v.u >> 16) & 1u);
  return (unsigned short)(r >> 16);
}
__device__ __forceinline__ float bf2f(unsigned short u) {
  union { unsigned int i; float f; } v; v.i = ((unsigned int)u) << 16; return v.f;
}

// ---------------- fp32 -> bf16 convert (vectorized) ----------------
__global__ void convert_f32_bf16(const float* __restrict__ in,
                                 unsigned short* __restrict__ out, int n4) {
  int i = blockIdx.x * 256 + threadIdx.x;
  if (i < n4) {
    float4 v = ((const float4*)in)[i];
    ushort4 o;
    o.x = f2bf(v.x); o.y = f2bf(v.y); o.z = f2bf(v.z); o.w = f2bf(v.w);
    ((ushort4*)out)[i] = o;
  }
}

// ---------------- bf16 GEMM: C(MxN) = A(MxK) * B(NxK)^T ----------------
// 128x128 tile, BK=32, 256 threads (4 waves, each 64x64), global_load_lds(16B)
template <bool OUT_BF16>
__global__ __launch_bounds__(256) void gemm_bt(
    const unsigned short* __restrict__ A,
    const unsigned short* __restrict__ Bm,
    void* __restrict__ Cv, int M, int N, int K)
{
  __shared__ unsigned short As[128 * 32];
  __shared__ unsigned short Bs[128 * 32];
  const int t = threadIdx.x;
  const int lane = t & 63, wave = t >> 6;
  const int quad = lane >> 4, rl = lane & 15;
  const int bm = blockIdx.x * 128, bn = blockIdx.y * 128;
  const int wm = (wave >> 1) * 64, wn = (wave & 1) * 64;
  const int ldsbase = (t & ~63) * 8;

  f32x4 acc[4][4];
#pragma unroll
  for (int i = 0; i < 4; i++)
#pragma unroll
    for (int j = 0; j < 4; j++) acc[i][j] = (f32x4){0.f, 0.f, 0.f, 0.f};

  for (int k0 = 0; k0 < K; k0 += 32) {
#pragma unroll
    for (int i = 0; i < 2; i++) {
      int e = (i * 256 + t) * 8;
      int row = e >> 5, col = e & 31;
      gl2lds16(A + (long)(bm + row) * K + k0 + col, As + i * 2048 + ldsbase);
      gl2lds16(Bm + (long)(bn + row) * K + k0 + col, Bs + i * 2048 + ldsbase);
    }
    __syncthreads();
    short8 af[4], bfr[4];
#pragma unroll
    for (int i = 0; i < 4; i++)
      af[i] = *(const short8*)(As + (wm + i * 16 + rl) * 32 + quad * 8);
#pragma unroll
    for (int j = 0; j < 4; j++)
      bfr[j] = *(const short8*)(Bs + (wn + j * 16 + rl) * 32 + quad * 8);
#pragma unroll
    for (int i = 0; i < 4; i++)
#pragma unroll
      for (int j = 0; j < 4; j++)
        acc[i][j] = __builtin_amdgcn_mfma_f32_16x16x32_bf16(af[i], bfr[j], acc[i][j], 0, 0, 0);
    __syncthreads();
  }
  // C/D layout: col = lane&15, row = quad*4 + reg  [verified m89/m91]
#pragma unroll
  for (int i = 0; i < 4; i++) {
    int row0 = bm + wm + i * 16 + quad * 4;
#pragma unroll
    for (int j = 0; j < 4; j++) {
      int col = bn + wn + j * 16 + rl;
#pragma unroll
      for (int r = 0; r < 4; r++) {
        if (OUT_BF16)
          ((unsigned short*)Cv)[(long)(row0 + r) * N + col] = f2bf(acc[i][j][r]);
        else
          ((float*)Cv)[(long)(row0 + r) * N + col] = acc[i][j][r];
      }
    }
  }
}

// ---------------- RMSNorm + RoPE + pack (Q and K only) ----------------
__global__ __launch_bounds__(256) void pack_norm_rope(
    const unsigned short* __restrict__ qkvg,
    const float* __restrict__ cosb, const float* __restrict__ sinb,
    const float* __restrict__ qw, const float* __restrict__ kw,
    unsigned short* __restrict__ qb, unsigned short* __restrict__ kb)
{
  int t = threadIdx.x, lane = t & 63, wave = t >> 6;
  long gw = (long)blockIdx.x * 4 + wave;       // 0 .. B*S*20-1
  int hu = (int)(gw % 20);
  long bs = gw / 20;                           // b*S + s
  int s = (int)(bs % S_);
  int b = (int)(bs / S_);
  const unsigned short* row = qkvg + bs * 5120;

  bool isq = hu < 16;
  const unsigned short* base = isq ? (row + hu * 128) : (row + 2048 + (hu - 16) * 128);
  float x1 = bf2f(base[lane]), x2 = bf2f(base[lane + 64]);
  float ss = x1 * x1 + x2 * x2;
#pragma unroll
  for (int m = 1; m < 64; m <<= 1) ss += __shfl_xor(ss, m, 64);
  float inv = rsqrtf(ss * (1.0f / 128.0f) + 1e-5f);
  const float* w = isq ? qw : kw;
  float n1 = x1 * inv * w[lane], n2 = x2 * inv * w[lane + 64];
  const float* cp = cosb + bs * 128;
  const float* sp = sinb + bs * 128;
  float o1 = n1 * cp[lane] - n2 * sp[lane];           // d < 64:  x*c - x2*s
  float o2 = n2 * cp[lane + 64] + n1 * sp[lane + 64]; // d >= 64: x*c + x1*s
  if (isq) {
    long o = ((long)(b * NH_ + hu) * S_ + s) * 128;
    qb[o + lane] = f2bf(o1); qb[o + lane + 64] = f2bf(o2);
  } else {
    long o = ((long)(b * NKV_ + (hu - 16)) * S_ + s) * 128;
    kb[o + lane] = f2bf(o1); kb[o + lane + 64] = f2bf(o2);
  }
  (void)s;
}

// ---------------- V transpose via LDS: qkvg v-cols -> vt [B,NKV,D,S] ----------
__global__ __launch_bounds__(256) void v_transpose(
    const unsigned short* __restrict__ qkvg, unsigned short* __restrict__ vt)
{
  __shared__ unsigned short tile[64][136];  // 64 s-rows x 128 d, +8 pad
  int t = threadIdx.x;
  int blk = blockIdx.x;                     // (b, kv, s-tile)
  int st = blk & 31, kv = (blk >> 5) & 3, b = blk >> 7;
  int s0 = st * 64;
#pragma unroll
  for (int i = 0; i < 4; i++) {
    int idx = i * 256 + t;                  // 0..1023 16B chunks
    int r = idx >> 4, c = (idx & 15) * 8;
    short8 v = *(const short8*)(qkvg + (long)(b * S_ + s0 + r) * 5120 + 2560 + kv * 128 + c);
    *(short8*)(&tile[r][c]) = v;
  }
  __syncthreads();
  long vo = (long)(b * NKV_ + kv) * 128;
#pragma unroll
  for (int i = 0; i < 8; i++) {
    int idx = i * 256 + t;                  // 0..2047
    int d = idx >> 4, sc = idx & 15;
    ushort4 o;
    o.x = tile[sc * 4 + 0][d]; o.y = tile[sc * 4 + 1][d];
    o.z = tile[sc * 4 + 2][d]; o.w = tile[sc * 4 + 3][d];
    *(ushort4*)(vt + (vo + d) * S_ + s0 + sc * 4) = o;
  }
}

// ---------------- flash attention, sliding window, fused gate ----------------
// 256 thr (4 waves), one block per (b, h, 64-row q tile). XOR-swizzled LDS:
// 16B chunk c of row r stored at physical chunk c ^ (r & 7) -> each 8-lane
// b128 phase covers all 32 banks (conflict-free).
__global__ __launch_bounds__(256, 4) void attn_kernel(
    const unsigned short* __restrict__ qb,   // [B,NH,S,D]
    const unsigned short* __restrict__ kbuf, // [B,NKV,S,D]
    const unsigned short* __restrict__ vt,   // [B,NKV,D,S]
    const unsigned short* __restrict__ qkvg, // gate at col 3072+
    unsigned short* __restrict__ aout)       // [B,S,NH*D] bf16
{
  __shared__ unsigned short Ks[64 * 128];   // (key, d) swizzled
  __shared__ unsigned short Vs[128 * 64];   // (d, key) swizzled
  __shared__ unsigned short Ps[4][16 * 64]; // per-wave P, swizzled
  int t = threadIdx.x, lane = t & 63, wave = t >> 6;
  int quad = lane >> 4, rl = lane & 15;
  int blk = blockIdx.x;
  int qt = 31 - (blk & 31);                  // heavy (17-tile) blocks first
  int h = (blk >> 5) & 15, b = blk >> 9;
  int kv = h >> 2;
  int q0 = qt * 64;

  const unsigned short* qrow =
      qb + (((long)(b * NH_ + h)) * S_ + q0 + wave * 16 + rl) * 128;
  short8 qf[4];
#pragma unroll
  for (int ks = 0; ks < 4; ks++) qf[ks] = *(const short8*)(qrow + ks * 32 + quad * 8);

  f32x4 oacc[8];
#pragma unroll
  for (int j = 0; j < 8; j++) oacc[j] = (f32x4){0.f, 0.f, 0.f, 0.f};
  float m_r[4] = {-1e9f, -1e9f, -1e9f, -1e9f};
  float l_r[4] = {0.f, 0.f, 0.f, 0.f};

  const unsigned short* kbase_p = kbuf + ((long)(b * NKV_ + kv)) * S_ * 128;
  const unsigned short* vbase_p = vt + ((long)(b * NKV_ + kv)) * 128 * S_;
  int t_lo = qt - 16; if (t_lo < 0) t_lo = 0;
  int rsw = rl & 7;                          // read-side swizzle key

  for (int kt = t_lo; kt <= qt; ++kt) {
    int kb0 = kt * 64;
    // ---- stage K,V global->VGPR->LDS (swizzled) ----
    short8 kreg[4], vreg[4];
#pragma unroll
    for (int i = 0; i < 4; i++) {
      int idx = i * 256 + t;
      { int r2 = idx >> 4, c2 = idx & 15;
        kreg[i] = *(const short8*)(kbase_p + (long)(kb0 + r2) * 128 + c2 * 8); }
      { int r2 = idx >> 3, c2 = idx & 7;
        vreg[i] = *(const short8*)(vbase_p + (long)r2 * S_ + kb0 + c2 * 8); }
    }
#pragma unroll
    for (int i = 0; i < 4; i++) {
      int idx = i * 256 + t;
      { int r2 = idx >> 4, c2 = idx & 15;
        *(short8*)(Ks + r2 * 128 + ((c2 ^ (r2 & 7)) * 8)) = kreg[i]; }
      { int r2 = idx >> 3, c2 = idx & 7;
        *(short8*)(Vs + r2 * 64 + ((c2 ^ (r2 & 7)) * 8)) = vreg[i]; }
    }
    __syncthreads();

    // ---- S = Q K^T ----
    f32x4 sc[4];
#pragma unroll
    for (int nt = 0; nt < 4; nt++) {
      f32x4 c = (f32x4){0.f, 0.f, 0.f, 0.f};
#pragma unroll
      for (int ks = 0; ks < 4; ks++) {
        short8 bfrag = *(const short8*)(Ks + (nt * 16 + rl) * 128 +
                                        (((ks * 4 + quad) ^ rsw) * 8));
        c = __builtin_amdgcn_mfma_f32_16x16x32_bf16(qf[ks], bfrag, c, 0, 0, 0);
      }
      sc[nt] = c;
    }
    const float scale = 0.08838834764831845f;  // 1/sqrt(128)
#pragma unroll
    for (int nt = 0; nt < 4; nt++)
#pragma unroll
      for (int r = 0; r < 4; r++) {
        int i_row = q0 + wave * 16 + quad * 4 + r;
        int j_col = kb0 + nt * 16 + rl;
        bool ok = (j_col <= i_row) && (i_row - j_col < WIN_);
        sc[nt][r] = ok ? sc[nt][r] * scale : -1e9f;
      }
    // ---- online softmax + P write (wave-private Ps: no barrier needed) ----
#pragma unroll
    for (int r = 0; r < 4; r++) {
      float mx = fmaxf(fmaxf(sc[0][r], sc[1][r]), fmaxf(sc[2][r], sc[3][r]));
#pragma unroll
      for (int m = 1; m < 16; m <<= 1) mx = fmaxf(mx, __shfl_xor(mx, m, 64));
      float newm = fmaxf(m_r[r], mx);
      float alpha = __expf(m_r[r] - newm);
      float p0 = __expf(sc[0][r] - newm), p1 = __expf(sc[1][r] - newm);
      float p2 = __expf(sc[2][r] - newm), p3 = __expf(sc[3][r] - newm);
      float rs = p0 + p1 + p2 + p3;
#pragma unroll
      for (int m = 1; m < 16; m <<= 1) rs += __shfl_xor(rs, m, 64);
      l_r[r] = l_r[r] * alpha + rs;
      m_r[r] = newm;
#pragma unroll
      for (int j = 0; j < 8; j++) oacc[j][r] *= alpha;
      int p = quad * 4 + r;
      int pbase = p * 64, psw = p & 7;
      int rlo = rl & 7, rhi = rl >> 3;
      Ps[wave][pbase + (((0 + rhi) ^ psw) * 8) + rlo] = f2bf(p0);
      Ps[wave][pbase + (((2 + rhi) ^ psw) * 8) + rlo] = f2bf(p1);
      Ps[wave][pbase + (((4 + rhi) ^ psw) * 8) + rlo] = f2bf(p2);
      Ps[wave][pbase + (((6 + rhi) ^ psw) * 8) + rlo] = f2bf(p3);
    }

    // ---- O += P V ----
#pragma unroll
    for (int ks2 = 0; ks2 < 2; ks2++) {
      short8 af2 = *(const short8*)(&Ps[wave][rl * 64 +
                                    (((ks2 * 4 + quad) ^ rsw) * 8)]);
#pragma unroll
      for (int j = 0; j < 8; j++) {
        short8 bf2 = *(const short8*)(Vs + (j * 16 + rl) * 64 +
                                      (((ks2 * 4 + quad) ^ rsw) * 8));
        oacc[j] = __builtin_amdgcn_mfma_f32_16x16x32_bf16(af2, bf2, oacc[j], 0, 0, 0);
      }
    }
    __syncthreads();  // Ks/Vs reads done before next tile's staging
  }

  // ---- epilogue: /l, * sigmoid(gate), write bf16 [B,S,NH*D] ----
#pragma unroll
  for (int r = 0; r < 4; r++) {
    int s_idx = q0 + wave * 16 + quad * 4 + r;
    float invl = 1.0f / l_r[r];
    long rowoff = (long)(b * S_ + s_idx);
    const unsigned short* grow = qkvg + rowoff * 5120 + 3072 + h * 128;
    unsigned short* orow = aout + rowoff * 2048 + h * 128;
#pragma unroll
    for (int j = 0; j < 8; j++) {
      int d = j * 16 + rl;
      float o = oacc[j][r] * invl;
      float g = bf2f(grow[d]);
      o = o / (1.0f + __expf(-g));
      orow[d] = f2bf(o);
    }
  }
}

extern "C" void kernel_launch(void* const* d_in, const int* in_sizes, int n_in,
                              void* d_out, int out_size, void* d_ws, size_t ws_size,
                              hipStream_t stream) {
  (void)in_sizes; (void)n_in; (void)out_size; (void)ws_size;
  const float* hs   = (const float*)d_in[0];
  const float* cosb = (const float*)d_in[1];
  const float* sinb = (const float*)d_in[2];
  // d_in[3] = attention_mask: analytic (causal sliding window), not read
  const float* Wq = (const float*)d_in[4];
  const float* Wk = (const float*)d_in[5];
  const float* Wv = (const float*)d_in[6];
  const float* Wo = (const float*)d_in[7];
  const float* Wg = (const float*)d_in[8];
  const float* qw = (const float*)d_in[9];
  const float* kw = (const float*)d_in[10];
  float* out = (float*)d_out;

  char* ws = (char*)d_ws;
  unsigned short* Xb   = (unsigned short*)ws; ws += (size_t)4096 * 2048 * 2;
  unsigned short* Wall = (unsigned short*)ws; ws += (size_t)5120 * 2048 * 2;
  unsigned short* Wob  = (unsigned short*)ws; ws += (size_t)2048 * 2048 * 2;
  unsigned short* qkvg = (unsigned short*)ws; ws += (size_t)4096 * 5120 * 2;
  unsigned short* qb   = (unsigned short*)ws; ws += (size_t)B_ * NH_ * S_ * D_ * 2;
  unsigned short* kbuf = (unsigned short*)ws; ws += (size_t)B_ * NKV_ * S_ * D_ * 2;
  unsigned short* vtb  = (unsigned short*)ws; ws += (size_t)B_ * NKV_ * S_ * D_ * 2;
  unsigned short* aout = (unsigned short*)ws; ws += (size_t)4096 * 2048 * 2;

  auto cvt = [&](const float* src, unsigned short* dst, long n) {
    int n4 = (int)(n / 4);
    convert_f32_bf16<<<(n4 + 255) / 256, 256, 0, stream>>>(src, dst, n4);
  };
  cvt(hs, Xb, (long)4096 * 2048);
  cvt(Wq, Wall, (long)2048 * 2048);
  cvt(Wk, Wall + (size_t)2048 * 2048, (long)512 * 2048);
  cvt(Wv, Wall + (size_t)2560 * 2048, (long)512 * 2048);
  cvt(Wg, Wall + (size_t)3072 * 2048, (long)2048 * 2048);
  cvt(Wo, Wob, (long)2048 * 2048);

  gemm_bt<true><<<dim3(32, 40), 256, 0, stream>>>(Xb, Wall, (void*)qkvg, 4096, 5120, 2048);
  pack_norm_rope<<<20480, 256, 0, stream>>>(qkvg, cosb, sinb, qw, kw, qb, kbuf);
  v_transpose<<<256, 256, 0, stream>>>(qkvg, vtb);
  attn_kernel<<<1024, 256, 0, stream>>>(qb, kbuf, vtb, qkvg, aout);
  gemm_bt<false><<<dim3(32, 16), 256, 0, stream>>>(aout, Wob, (void*)out, 4096, 2048, 2048);
}

// Round 3
// 439.536 us; speedup vs baseline: 1.2112x; 1.2112x over previous
//
#include <hip/hip_runtime.h>
#include <hip/hip_bf16.h>

#define B_    2
#define S_    2048
#define H_    2048
#define NH_   16
#define NKV_  4
#define D_    128
#define WIN_  1024

typedef __attribute__((ext_vector_type(8))) short short8;
typedef __attribute__((ext_vector_type(4))) float f32x4;

__device__ __forceinline__ void gl2lds16(const void* g, void* l) {
  __builtin_amdgcn_global_load_lds(
      (const __attribute__((address_space(1))) void*)g,
      (__attribute__((address_space(3))) void*)l, 16, 0, 0);
}

__device__ __forceinline__ unsigned short f2bf(float x) {
  union { float f; unsigned int u; } v; v.f = x;
  unsigned int r = v.u + 0x7fffu + ((v.u >> 16) & 1u);
  return (unsigned short)(r >> 16);
}
__device__ __forceinline__ float bf2f(unsigned short u) {
  union { unsigned int i; float f; } v; v.i = ((unsigned int)u) << 16; return v.f;
}

// ---------------- fp32 -> bf16 convert (vectorized) ----------------
__global__ void convert_f32_bf16(const float* __restrict__ in,
                                 unsigned short* __restrict__ out, int n4) {
  int i = blockIdx.x * 256 + threadIdx.x;
  if (i < n4) {
    float4 v = ((const float4*)in)[i];
    ushort4 o;
    o.x = f2bf(v.x); o.y = f2bf(v.y); o.z = f2bf(v.z); o.w = f2bf(v.w);
    ((ushort4*)out)[i] = o;
  }
}

// ---------------- bf16 GEMM: C(MxN) = A(MxK) * B(NxK)^T ----------------
template <bool OUT_BF16>
__global__ __launch_bounds__(256) void gemm_bt(
    const unsigned short* __restrict__ A,
    const unsigned short* __restrict__ Bm,
    void* __restrict__ Cv, int M, int N, int K)
{
  __shared__ unsigned short As[128 * 32];
  __shared__ unsigned short Bs[128 * 32];
  const int t = threadIdx.x;
  const int lane = t & 63, wave = t >> 6;
  const int quad = lane >> 4, rl = lane & 15;
  const int bm = blockIdx.x * 128, bn = blockIdx.y * 128;
  const int wm = (wave >> 1) * 64, wn = (wave & 1) * 64;
  const int ldsbase = (t & ~63) * 8;

  f32x4 acc[4][4];
#pragma unroll
  for (int i = 0; i < 4; i++)
#pragma unroll
    for (int j = 0; j < 4; j++) acc[i][j] = (f32x4){0.f, 0.f, 0.f, 0.f};

  for (int k0 = 0; k0 < K; k0 += 32) {
#pragma unroll
    for (int i = 0; i < 2; i++) {
      int e = (i * 256 + t) * 8;
      int row = e >> 5, col = e & 31;
      gl2lds16(A + (long)(bm + row) * K + k0 + col, As + i * 2048 + ldsbase);
      gl2lds16(Bm + (long)(bn + row) * K + k0 + col, Bs + i * 2048 + ldsbase);
    }
    __syncthreads();
    short8 af[4], bfr[4];
#pragma unroll
    for (int i = 0; i < 4; i++)
      af[i] = *(const short8*)(As + (wm + i * 16 + rl) * 32 + quad * 8);
#pragma unroll
    for (int j = 0; j < 4; j++)
      bfr[j] = *(const short8*)(Bs + (wn + j * 16 + rl) * 32 + quad * 8);
#pragma unroll
    for (int i = 0; i < 4; i++)
#pragma unroll
      for (int j = 0; j < 4; j++)
        acc[i][j] = __builtin_amdgcn_mfma_f32_16x16x32_bf16(af[i], bfr[j], acc[i][j], 0, 0, 0);
    __syncthreads();
  }
#pragma unroll
  for (int i = 0; i < 4; i++) {
    int row0 = bm + wm + i * 16 + quad * 4;
#pragma unroll
    for (int j = 0; j < 4; j++) {
      int col = bn + wn + j * 16 + rl;
#pragma unroll
      for (int r = 0; r < 4; r++) {
        if (OUT_BF16)
          ((unsigned short*)Cv)[(long)(row0 + r) * N + col] = f2bf(acc[i][j][r]);
        else
          ((float*)Cv)[(long)(row0 + r) * N + col] = acc[i][j][r];
      }
    }
  }
}

// ---------------- RMSNorm + RoPE + pack (Q and K only) ----------------
__global__ __launch_bounds__(256) void pack_norm_rope(
    const unsigned short* __restrict__ qkvg,
    const float* __restrict__ cosb, const float* __restrict__ sinb,
    const float* __restrict__ qw, const float* __restrict__ kw,
    unsigned short* __restrict__ qb, unsigned short* __restrict__ kb)
{
  int t = threadIdx.x, lane = t & 63, wave = t >> 6;
  long gw = (long)blockIdx.x * 4 + wave;
  int hu = (int)(gw % 20);
  long bs = gw / 20;
  int b = (int)(bs / S_);
  int s = (int)(bs % S_);
  const unsigned short* row = qkvg + bs * 5120;

  bool isq = hu < 16;
  const unsigned short* base = isq ? (row + hu * 128) : (row + 2048 + (hu - 16) * 128);
  float x1 = bf2f(base[lane]), x2 = bf2f(base[lane + 64]);
  float ss = x1 * x1 + x2 * x2;
#pragma unroll
  for (int m = 1; m < 64; m <<= 1) ss += __shfl_xor(ss, m, 64);
  float inv = rsqrtf(ss * (1.0f / 128.0f) + 1e-5f);
  const float* w = isq ? qw : kw;
  float n1 = x1 * inv * w[lane], n2 = x2 * inv * w[lane + 64];
  const float* cp = cosb + bs * 128;
  const float* sp = sinb + bs * 128;
  float o1 = n1 * cp[lane] - n2 * sp[lane];
  float o2 = n2 * cp[lane + 64] + n1 * sp[lane + 64];
  if (isq) {
    long o = ((long)(b * NH_ + hu) * S_ + s) * 128;
    qb[o + lane] = f2bf(o1); qb[o + lane + 64] = f2bf(o2);
  } else {
    long o = ((long)(b * NKV_ + (hu - 16)) * S_ + s) * 128;
    kb[o + lane] = f2bf(o1); kb[o + lane + 64] = f2bf(o2);
  }
}

// ---------------- V transpose via LDS: qkvg v-cols -> vt [B,NKV,D,S] ----------
__global__ __launch_bounds__(256) void v_transpose(
    const unsigned short* __restrict__ qkvg, unsigned short* __restrict__ vt)
{
  __shared__ unsigned short tile[64][136];
  int t = threadIdx.x;
  int blk = blockIdx.x;
  int st = blk & 31, kv = (blk >> 5) & 3, b = blk >> 7;
  int s0 = st * 64;
#pragma unroll
  for (int i = 0; i < 4; i++) {
    int idx = i * 256 + t;
    int r = idx >> 4, c = (idx & 15) * 8;
    short8 v = *(const short8*)(qkvg + (long)(b * S_ + s0 + r) * 5120 + 2560 + kv * 128 + c);
    *(short8*)(&tile[r][c]) = v;
  }
  __syncthreads();
  long vo = (long)(b * NKV_ + kv) * 128;
#pragma unroll
  for (int i = 0; i < 8; i++) {
    int idx = i * 256 + t;
    int d = idx >> 4, sc = idx & 15;
    ushort4 o;
    o.x = tile[sc * 4 + 0][d]; o.y = tile[sc * 4 + 1][d];
    o.z = tile[sc * 4 + 2][d]; o.w = tile[sc * 4 + 3][d];
    *(ushort4*)(vt + (vo + d) * S_ + s0 + sc * 4) = o;
  }
}

// ---------------- flash attention: 1 block per (b,kv,qt), GQA-shared K/V ----
// 512 thr = 8 waves. Wave w: head h = kv*4 + (w>>1), q rows [q0+(w&1)*32, +32).
// Padded LDS rows (stride = row+16B): worst-case 2-way bank conflict (free).
// Prefetch next K/V tile into VGPRs during compute (global latency hidden).
#define KSTR 136   // 128 + 8 shorts
#define VSTR 72    // 64 + 8 shorts
__global__ __launch_bounds__(512, 2) void attn_kernel(
    const unsigned short* __restrict__ qb,   // [B,NH,S,D]
    const unsigned short* __restrict__ kbuf, // [B,NKV,S,D]
    const unsigned short* __restrict__ vt,   // [B,NKV,D,S]
    const unsigned short* __restrict__ qkvg, // gate at col 3072+
    unsigned short* __restrict__ aout)       // [B,S,NH*D] bf16
{
  __shared__ unsigned short Ks[64 * KSTR];      // (key, d) padded
  __shared__ unsigned short Vs[128 * VSTR];     // (d, key) padded
  __shared__ unsigned short Ps[8][2][16 * VSTR];// per-wave, per-mtile P
  int t = threadIdx.x, lane = t & 63, wave = t >> 6;
  int quad = lane >> 4, rl = lane & 15;
  int blk = blockIdx.x;
  int qt = 31 - (blk & 31);                  // heavy blocks dispatch first
  int kv = (blk >> 5) & 3, b = blk >> 7;
  int h = kv * 4 + (wave >> 1);
  int half = wave & 1;
  int q0 = qt * 64;

  // Q fragments: 32 q rows = 2 mtiles of 16
  const unsigned short* qhead = qb + (((long)(b * NH_ + h)) * S_) * 128;
  short8 qf[2][4];
#pragma unroll
  for (int mt = 0; mt < 2; mt++)
#pragma unroll
    for (int ks = 0; ks < 4; ks++)
      qf[mt][ks] = *(const short8*)(qhead +
          (long)(q0 + half * 32 + mt * 16 + rl) * 128 + ks * 32 + quad * 8);

  f32x4 oacc[2][8];
#pragma unroll
  for (int mt = 0; mt < 2; mt++)
#pragma unroll
    for (int j = 0; j < 8; j++) oacc[mt][j] = (f32x4){0.f, 0.f, 0.f, 0.f};
  float m_r[2][4], l_r[2][4];
#pragma unroll
  for (int mt = 0; mt < 2; mt++)
#pragma unroll
    for (int r = 0; r < 4; r++) { m_r[mt][r] = -1e9f; l_r[mt][r] = 0.f; }

  const unsigned short* kbase_p = kbuf + ((long)(b * NKV_ + kv)) * S_ * 128;
  const unsigned short* vbase_p = vt + ((long)(b * NKV_ + kv)) * 128 * S_;
  int t_lo = qt - 16; if (t_lo < 0) t_lo = 0;

  // K chunk idx for this thread: 1024 chunks, 512 threads -> 2 each
  int kr0 = t >> 4, kc0 = (t & 15) * 8;
  int kr1 = (t + 512) >> 4, kc1 = ((t + 512) & 15) * 8;
  int vr0 = t >> 3, vc0 = (t & 7) * 8;
  int vr1 = (t + 512) >> 3, vc1 = ((t + 512) & 7) * 8;

  // prologue: stage first tile
  {
    int kb0 = t_lo * 64;
    short8 k0v = *(const short8*)(kbase_p + (long)(kb0 + kr0) * 128 + kc0);
    short8 k1v = *(const short8*)(kbase_p + (long)(kb0 + kr1) * 128 + kc1);
    short8 v0v = *(const short8*)(vbase_p + (long)vr0 * S_ + kb0 + vc0);
    short8 v1v = *(const short8*)(vbase_p + (long)vr1 * S_ + kb0 + vc1);
    *(short8*)(Ks + kr0 * KSTR + kc0) = k0v;
    *(short8*)(Ks + kr1 * KSTR + kc1) = k1v;
    *(short8*)(Vs + vr0 * VSTR + vc0) = v0v;
    *(short8*)(Vs + vr1 * VSTR + vc1) = v1v;
  }
  __syncthreads();

  const float scale = 0.08838834764831845f;  // 1/sqrt(128)
  for (int kt = t_lo; kt <= qt; ++kt) {
    int kb0 = kt * 64;
    // prefetch next tile into VGPRs (in flight during compute)
    short8 k0v, k1v, v0v, v1v;
    if (kt < qt) {
      int nb0 = kb0 + 64;
      k0v = *(const short8*)(kbase_p + (long)(nb0 + kr0) * 128 + kc0);
      k1v = *(const short8*)(kbase_p + (long)(nb0 + kr1) * 128 + kc1);
      v0v = *(const short8*)(vbase_p + (long)vr0 * S_ + nb0 + vc0);
      v1v = *(const short8*)(vbase_p + (long)vr1 * S_ + nb0 + vc1);
    }

    // ---- S = Q K^T (both mtiles share each K fragment) ----
    f32x4 sc[2][4];
#pragma unroll
    for (int nt = 0; nt < 4; nt++) {
      f32x4 c0 = (f32x4){0.f, 0.f, 0.f, 0.f};
      f32x4 c1 = (f32x4){0.f, 0.f, 0.f, 0.f};
#pragma unroll
      for (int ks = 0; ks < 4; ks++) {
        short8 bfrag = *(const short8*)(Ks + (nt * 16 + rl) * KSTR + (ks * 4 + quad) * 8);
        c0 = __builtin_amdgcn_mfma_f32_16x16x32_bf16(qf[0][ks], bfrag, c0, 0, 0, 0);
        c1 = __builtin_amdgcn_mfma_f32_16x16x32_bf16(qf[1][ks], bfrag, c1, 0, 0, 0);
      }
      sc[0][nt] = c0; sc[1][nt] = c1;
    }
    // ---- mask + online softmax + P write ----
#pragma unroll
    for (int mt = 0; mt < 2; mt++) {
#pragma unroll
      for (int nt = 0; nt < 4; nt++)
#pragma unroll
        for (int r = 0; r < 4; r++) {
          int i_row = q0 + half * 32 + mt * 16 + quad * 4 + r;
          int j_col = kb0 + nt * 16 + rl;
          bool ok = (j_col <= i_row) && (i_row - j_col < WIN_);
          sc[mt][nt][r] = ok ? sc[mt][nt][r] * scale : -1e9f;
        }
#pragma unroll
      for (int r = 0; r < 4; r++) {
        float mx = fmaxf(fmaxf(sc[mt][0][r], sc[mt][1][r]),
                         fmaxf(sc[mt][2][r], sc[mt][3][r]));
#pragma unroll
        for (int m = 1; m < 16; m <<= 1) mx = fmaxf(mx, __shfl_xor(mx, m, 64));
        float newm = fmaxf(m_r[mt][r], mx);
        float alpha = __expf(m_r[mt][r] - newm);
        float p0 = __expf(sc[mt][0][r] - newm), p1 = __expf(sc[mt][1][r] - newm);
        float p2 = __expf(sc[mt][2][r] - newm), p3 = __expf(sc[mt][3][r] - newm);
        float rs = p0 + p1 + p2 + p3;
#pragma unroll
        for (int m = 1; m < 16; m <<= 1) rs += __shfl_xor(rs, m, 64);
        l_r[mt][r] = l_r[mt][r] * alpha + rs;
        m_r[mt][r] = newm;
#pragma unroll
        for (int j = 0; j < 8; j++) oacc[mt][j][r] *= alpha;
        int prow = (quad * 4 + r) * VSTR;
        unsigned short* pw = &Ps[wave][mt][prow];
        pw[0 * 16 + rl] = f2bf(p0);
        pw[1 * 16 + rl] = f2bf(p1);
        pw[2 * 16 + rl] = f2bf(p2);
        pw[3 * 16 + rl] = f2bf(p3);
      }
    }
    // ---- O += P V (V fragment shared by both mtiles; wave-private Ps) ----
#pragma unroll
    for (int ks2 = 0; ks2 < 2; ks2++) {
      short8 af0 = *(const short8*)(&Ps[wave][0][rl * VSTR + (ks2 * 4 + quad) * 8]);
      short8 af1 = *(const short8*)(&Ps[wave][1][rl * VSTR + (ks2 * 4 + quad) * 8]);
#pragma unroll
      for (int j = 0; j < 8; j++) {
        short8 bf2 = *(const short8*)(Vs + (j * 16 + rl) * VSTR + (ks2 * 4 + quad) * 8);
        oacc[0][j] = __builtin_amdgcn_mfma_f32_16x16x32_bf16(af0, bf2, oacc[0][j], 0, 0, 0);
        oacc[1][j] = __builtin_amdgcn_mfma_f32_16x16x32_bf16(af1, bf2, oacc[1][j], 0, 0, 0);
      }
    }
    if (kt < qt) {
      __syncthreads();   // all LDS reads of this tile done
      *(short8*)(Ks + kr0 * KSTR + kc0) = k0v;
      *(short8*)(Ks + kr1 * KSTR + kc1) = k1v;
      *(short8*)(Vs + vr0 * VSTR + vc0) = v0v;
      *(short8*)(Vs + vr1 * VSTR + vc1) = v1v;
      __syncthreads();   // next tile visible
    }
  }

  // ---- epilogue: /l, * sigmoid(gate), write bf16 [B,S,NH*D] ----
#pragma unroll
  for (int mt = 0; mt < 2; mt++)
#pragma unroll
    for (int r = 0; r < 4; r++) {
      int s_idx = q0 + half * 32 + mt * 16 + quad * 4 + r;
      float invl = 1.0f / l_r[mt][r];
      long rowoff = (long)(b * S_ + s_idx);
      const unsigned short* grow = qkvg + rowoff * 5120 + 3072 + h * 128;
      unsigned short* orow = aout + rowoff * 2048 + h * 128;
#pragma unroll
      for (int j = 0; j < 8; j++) {
        int d = j * 16 + rl;
        float o = oacc[mt][j][r] * invl;
        float g = bf2f(grow[d]);
        o = o / (1.0f + __expf(-g));
        orow[d] = f2bf(o);
      }
    }
}

extern "C" void kernel_launch(void* const* d_in, const int* in_sizes, int n_in,
                              void* d_out, int out_size, void* d_ws, size_t ws_size,
                              hipStream_t stream) {
  (void)in_sizes; (void)n_in; (void)out_size; (void)ws_size;
  const float* hs   = (const float*)d_in[0];
  const float* cosb = (const float*)d_in[1];
  const float* sinb = (const float*)d_in[2];
  const float* Wq = (const float*)d_in[4];
  const float* Wk = (const float*)d_in[5];
  const float* Wv = (const float*)d_in[6];
  const float* Wo = (const float*)d_in[7];
  const float* Wg = (const float*)d_in[8];
  const float* qw = (const float*)d_in[9];
  const float* kw = (const float*)d_in[10];
  float* out = (float*)d_out;

  char* ws = (char*)d_ws;
  unsigned short* Xb   = (unsigned short*)ws; ws += (size_t)4096 * 2048 * 2;
  unsigned short* Wall = (unsigned short*)ws; ws += (size_t)5120 * 2048 * 2;
  unsigned short* Wob  = (unsigned short*)ws; ws += (size_t)2048 * 2048 * 2;
  unsigned short* qkvg = (unsigned short*)ws; ws += (size_t)4096 * 5120 * 2;
  unsigned short* qb   = (unsigned short*)ws; ws += (size_t)B_ * NH_ * S_ * D_ * 2;
  unsigned short* kbuf = (unsigned short*)ws; ws += (size_t)B_ * NKV_ * S_ * D_ * 2;
  unsigned short* vtb  = (unsigned short*)ws; ws += (size_t)B_ * NKV_ * S_ * D_ * 2;
  unsigned short* aout = (unsigned short*)ws; ws += (size_t)4096 * 2048 * 2;

  auto cvt = [&](const float* src, unsigned short* dst, long n) {
    int n4 = (int)(n / 4);
    convert_f32_bf16<<<(n4 + 255) / 256, 256, 0, stream>>>(src, dst, n4);
  };
  cvt(hs, Xb, (long)4096 * 2048);
  cvt(Wq, Wall, (long)2048 * 2048);
  cvt(Wk, Wall + (size_t)2048 * 2048, (long)512 * 2048);
  cvt(Wv, Wall + (size_t)2560 * 2048, (long)512 * 2048);
  cvt(Wg, Wall + (size_t)3072 * 2048, (long)2048 * 2048);
  cvt(Wo, Wob, (long)2048 * 2048);

  gemm_bt<true><<<dim3(32, 40), 256, 0, stream>>>(Xb, Wall, (void*)qkvg, 4096, 5120, 2048);
  pack_norm_rope<<<20480, 256, 0, stream>>>(qkvg, cosb, sinb, qw, kw, qb, kbuf);
  v_transpose<<<256, 256, 0, stream>>>(qkvg, vtb);
  attn_kernel<<<256, 512, 0, stream>>>(qb, kbuf, vtb, qkvg, aout);
  gemm_bt<false><<<dim3(32, 16), 256, 0, stream>>>(aout, Wob, (void*)out, 4096, 2048, 2048);
}

// Round 5
// 421.039 us; speedup vs baseline: 1.2644x; 1.0439x over previous
//
#include <hip/hip_runtime.h>
#include <hip/hip_bf16.h>

#define B_    2
#define S_    2048
#define H_    2048
#define NH_   16
#define NKV_  4
#define D_    128
#define WIN_  1024

typedef __attribute__((ext_vector_type(8))) short short8;
typedef __attribute__((ext_vector_type(4))) float f32x4;

__device__ __forceinline__ void gl2lds16(const void* g, void* l) {
  __builtin_amdgcn_global_load_lds(
      (const __attribute__((address_space(1))) void*)g,
      (__attribute__((address_space(3))) void*)l, 16, 0, 0);
}

__device__ __forceinline__ unsigned short f2bf(float x) {
  union { float f; unsigned int u; } v; v.f = x;
  unsigned int r = v.u + 0x7fffu + ((v.u >> 16) & 1u);
  return (unsigned short)(r >> 16);
}
__device__ __forceinline__ float bf2f(unsigned short u) {
  union { unsigned int i; float f; } v; v.i = ((unsigned int)u) << 16; return v.f;
}

// ---------------- fused fp32 -> bf16 convert, all 6 tensors in one launch ----
// float4-chunk segment boundaries (compile-time):
//  hs 2,097,152 | Wq +1,048,576 | Wk +262,144 | Wv +262,144 | Wg +1,048,576 | Wo +1,048,576
// TOTAL = 5,767,168 chunks = 22,528 blocks x 256. (R4 bug: launched 22,524.)
#define CVT_TOTAL 5767168L
__global__ __launch_bounds__(256) void convert_all(
    const float* __restrict__ hs, const float* __restrict__ wq,
    const float* __restrict__ wk, const float* __restrict__ wv,
    const float* __restrict__ wg, const float* __restrict__ wo,
    unsigned short* __restrict__ xb, unsigned short* __restrict__ wall,
    unsigned short* __restrict__ wob) {
  long i = (long)blockIdx.x * 256 + threadIdx.x;
  if (i >= CVT_TOTAL) return;
  const float4* src; ushort4* dst;
  if (i < 2097152)      { src = (const float4*)hs + i;                         dst = (ushort4*)xb + i; }
  else if (i < 3145728) { long j = i - 2097152; src = (const float4*)wq + j;   dst = (ushort4*)wall + j; }
  else if (i < 3407872) { long j = i - 3145728; src = (const float4*)wk + j;   dst = (ushort4*)wall + 1048576 + j; }
  else if (i < 3670016) { long j = i - 3407872; src = (const float4*)wv + j;   dst = (ushort4*)wall + 1310720 + j; }
  else if (i < 4718592) { long j = i - 3670016; src = (const float4*)wg + j;   dst = (ushort4*)wall + 1572864 + j; }
  else                  { long j = i - 4718592; src = (const float4*)wo + j;   dst = (ushort4*)wob + j; }
  float4 v = *src;
  ushort4 o; o.x = f2bf(v.x); o.y = f2bf(v.y); o.z = f2bf(v.z); o.w = f2bf(v.w);
  *dst = o;
}

// ---------------- bf16 GEMM: C(MxN) = A(MxK) * B(NxK)^T ----------------
// 128x128 tile, BK=32, 256 threads, global_load_lds(16B).
// LDS chunk swizzle: physical 16B chunk tt holds logical chunk (tt&3)^((row>>1)&3)
// of row tt>>2 — applied at the GLOBAL read side (permutation within each 64B
// row, coalescing preserved; global_load_lds write layout stays contiguous).
// Fragment reads fetch physical chunk quad^((row>>1)&3) -> logical chunk quad;
// per-8-lane b128 phase covers bank bases {0,4,..,28} = all 32 banks.
template <bool OUT_BF16>
__global__ __launch_bounds__(256) void gemm_bt(
    const unsigned short* __restrict__ A,
    const unsigned short* __restrict__ Bm,
    void* __restrict__ Cv, int M, int N, int K)
{
  __shared__ unsigned short As[128 * 32];
  __shared__ unsigned short Bs[128 * 32];
  const int t = threadIdx.x;
  const int lane = t & 63, wave = t >> 6;
  const int quad = lane >> 4, rl = lane & 15;
  const int bm = blockIdx.x * 128, bn = blockIdx.y * 128;
  const int wm = (wave >> 1) * 64, wn = (wave & 1) * 64;
  const int ldsbase = (t & ~63) * 8;

  f32x4 acc[4][4];
#pragma unroll
  for (int i = 0; i < 4; i++)
#pragma unroll
    for (int j = 0; j < 4; j++) acc[i][j] = (f32x4){0.f, 0.f, 0.f, 0.f};

  for (int k0 = 0; k0 < K; k0 += 32) {
#pragma unroll
    for (int i = 0; i < 2; i++) {
      int tt = i * 256 + t;                    // physical 16B-chunk id
      int row = tt >> 2;
      int cl = (tt & 3) ^ ((row >> 1) & 3);    // logical chunk to fetch
      gl2lds16(A + (long)(bm + row) * K + k0 + cl * 8, As + i * 2048 + ldsbase);
      gl2lds16(Bm + (long)(bn + row) * K + k0 + cl * 8, Bs + i * 2048 + ldsbase);
    }
    __syncthreads();
    short8 af[4], bfr[4];
#pragma unroll
    for (int i = 0; i < 4; i++) {
      int row = wm + i * 16 + rl;
      af[i] = *(const short8*)(As + row * 32 + ((quad ^ ((row >> 1) & 3)) * 8));
    }
#pragma unroll
    for (int j = 0; j < 4; j++) {
      int row = wn + j * 16 + rl;
      bfr[j] = *(const short8*)(Bs + row * 32 + ((quad ^ ((row >> 1) & 3)) * 8));
    }
#pragma unroll
    for (int i = 0; i < 4; i++)
#pragma unroll
      for (int j = 0; j < 4; j++)
        acc[i][j] = __builtin_amdgcn_mfma_f32_16x16x32_bf16(af[i], bfr[j], acc[i][j], 0, 0, 0);
    __syncthreads();
  }
#pragma unroll
  for (int i = 0; i < 4; i++) {
    int row0 = bm + wm + i * 16 + quad * 4;
#pragma unroll
    for (int j = 0; j < 4; j++) {
      int col = bn + wn + j * 16 + rl;
#pragma unroll
      for (int r = 0; r < 4; r++) {
        if (OUT_BF16)
          ((unsigned short*)Cv)[(long)(row0 + r) * N + col] = f2bf(acc[i][j][r]);
        else
          ((float*)Cv)[(long)(row0 + r) * N + col] = acc[i][j][r];
      }
    }
  }
}

// ---------------- RMSNorm + RoPE + pack (Q and K only) ----------------
__global__ __launch_bounds__(256) void pack_norm_rope(
    const unsigned short* __restrict__ qkvg,
    const float* __restrict__ cosb, const float* __restrict__ sinb,
    const float* __restrict__ qw, const float* __restrict__ kw,
    unsigned short* __restrict__ qb, unsigned short* __restrict__ kb)
{
  int t = threadIdx.x, lane = t & 63, wave = t >> 6;
  long gw = (long)blockIdx.x * 4 + wave;
  int hu = (int)(gw % 20);
  long bs = gw / 20;
  int b = (int)(bs / S_);
  int s = (int)(bs % S_);
  const unsigned short* row = qkvg + bs * 5120;

  bool isq = hu < 16;
  const unsigned short* base = isq ? (row + hu * 128) : (row + 2048 + (hu - 16) * 128);
  float x1 = bf2f(base[lane]), x2 = bf2f(base[lane + 64]);
  float ss = x1 * x1 + x2 * x2;
#pragma unroll
  for (int m = 1; m < 64; m <<= 1) ss += __shfl_xor(ss, m, 64);
  float inv = rsqrtf(ss * (1.0f / 128.0f) + 1e-5f);
  const float* w = isq ? qw : kw;
  float n1 = x1 * inv * w[lane], n2 = x2 * inv * w[lane + 64];
  const float* cp = cosb + bs * 128;
  const float* sp = sinb + bs * 128;
  float o1 = n1 * cp[lane] - n2 * sp[lane];
  float o2 = n2 * cp[lane + 64] + n1 * sp[lane + 64];
  if (isq) {
    long o = ((long)(b * NH_ + hu) * S_ + s) * 128;
    qb[o + lane] = f2bf(o1); qb[o + lane + 64] = f2bf(o2);
  } else {
    long o = ((long)(b * NKV_ + (hu - 16)) * S_ + s) * 128;
    kb[o + lane] = f2bf(o1); kb[o + lane + 64] = f2bf(o2);
  }
}

// ---------------- V transpose via LDS: qkvg v-cols -> vt [B,NKV,D,S] ----------
__global__ __launch_bounds__(256) void v_transpose(
    const unsigned short* __restrict__ qkvg, unsigned short* __restrict__ vt)
{
  __shared__ unsigned short tile[64][136];
  int t = threadIdx.x;
  int blk = blockIdx.x;
  int st = blk & 31, kv = (blk >> 5) & 3, b = blk >> 7;
  int s0 = st * 64;
#pragma unroll
  for (int i = 0; i < 4; i++) {
    int idx = i * 256 + t;
    int r = idx >> 4, c = (idx & 15) * 8;
    short8 v = *(const short8*)(qkvg + (long)(b * S_ + s0 + r) * 5120 + 2560 + kv * 128 + c);
    *(short8*)(&tile[r][c]) = v;
  }
  __syncthreads();
  long vo = (long)(b * NKV_ + kv) * 128;
#pragma unroll
  for (int i = 0; i < 8; i++) {
    int idx = i * 256 + t;
    int d = idx >> 4, sc = idx & 15;
    ushort4 o;
    o.x = tile[sc * 4 + 0][d]; o.y = tile[sc * 4 + 1][d];
    o.z = tile[sc * 4 + 2][d]; o.w = tile[sc * 4 + 3][d];
    *(ushort4*)(vt + (vo + d) * S_ + s0 + sc * 4) = o;
  }
}

// ---------------- flash attention: 1 block per (b,kv,qt), GQA-shared K/V ----
#define KSTR 136   // 128 + 8 shorts
#define VSTR 72    // 64 + 8 shorts
__global__ __launch_bounds__(512, 2) void attn_kernel(
    const unsigned short* __restrict__ qb,   // [B,NH,S,D]
    const unsigned short* __restrict__ kbuf, // [B,NKV,S,D]
    const unsigned short* __restrict__ vt,   // [B,NKV,D,S]
    const unsigned short* __restrict__ qkvg, // gate at col 3072+
    unsigned short* __restrict__ aout)       // [B,S,NH*D] bf16
{
  __shared__ unsigned short Ks[64 * KSTR];      // (key, d) padded
  __shared__ unsigned short Vs[128 * VSTR];     // (d, key) padded
  __shared__ unsigned short Ps[8][2][16 * VSTR];// per-wave, per-mtile P
  int t = threadIdx.x, lane = t & 63, wave = t >> 6;
  int quad = lane >> 4, rl = lane & 15;
  int blk = blockIdx.x;
  int qt = 31 - (blk & 31);                  // heavy blocks dispatch first
  int kv = (blk >> 5) & 3, b = blk >> 7;
  int h = kv * 4 + (wave >> 1);
  int half = wave & 1;
  int q0 = qt * 64;

  const unsigned short* qhead = qb + (((long)(b * NH_ + h)) * S_) * 128;
  short8 qf[2][4];
#pragma unroll
  for (int mt = 0; mt < 2; mt++)
#pragma unroll
    for (int ks = 0; ks < 4; ks++)
      qf[mt][ks] = *(const short8*)(qhead +
          (long)(q0 + half * 32 + mt * 16 + rl) * 128 + ks * 32 + quad * 8);

  f32x4 oacc[2][8];
#pragma unroll
  for (int mt = 0; mt < 2; mt++)
#pragma unroll
    for (int j = 0; j < 8; j++) oacc[mt][j] = (f32x4){0.f, 0.f, 0.f, 0.f};
  float m_r[2][4], l_r[2][4];
#pragma unroll
  for (int mt = 0; mt < 2; mt++)
#pragma unroll
    for (int r = 0; r < 4; r++) { m_r[mt][r] = -1e9f; l_r[mt][r] = 0.f; }

  const unsigned short* kbase_p = kbuf + ((long)(b * NKV_ + kv)) * S_ * 128;
  const unsigned short* vbase_p = vt + ((long)(b * NKV_ + kv)) * 128 * S_;
  int t_lo = qt - 16; if (t_lo < 0) t_lo = 0;

  int kr0 = t >> 4, kc0 = (t & 15) * 8;
  int kr1 = (t + 512) >> 4, kc1 = ((t + 512) & 15) * 8;
  int vr0 = t >> 3, vc0 = (t & 7) * 8;
  int vr1 = (t + 512) >> 3, vc1 = ((t + 512) & 7) * 8;

  {
    int kb0 = t_lo * 64;
    short8 k0v = *(const short8*)(kbase_p + (long)(kb0 + kr0) * 128 + kc0);
    short8 k1v = *(const short8*)(kbase_p + (long)(kb0 + kr1) * 128 + kc1);
    short8 v0v = *(const short8*)(vbase_p + (long)vr0 * S_ + kb0 + vc0);
    short8 v1v = *(const short8*)(vbase_p + (long)vr1 * S_ + kb0 + vc1);
    *(short8*)(Ks + kr0 * KSTR + kc0) = k0v;
    *(short8*)(Ks + kr1 * KSTR + kc1) = k1v;
    *(short8*)(Vs + vr0 * VSTR + vc0) = v0v;
    *(short8*)(Vs + vr1 * VSTR + vc1) = v1v;
  }
  __syncthreads();

  const float scale = 0.08838834764831845f;  // 1/sqrt(128)
  for (int kt = t_lo; kt <= qt; ++kt) {
    int kb0 = kt * 64;
    short8 k0v, k1v, v0v, v1v;
    if (kt < qt) {
      int nb0 = kb0 + 64;
      k0v = *(const short8*)(kbase_p + (long)(nb0 + kr0) * 128 + kc0);
      k1v = *(const short8*)(kbase_p + (long)(nb0 + kr1) * 128 + kc1);
      v0v = *(const short8*)(vbase_p + (long)vr0 * S_ + nb0 + vc0);
      v1v = *(const short8*)(vbase_p + (long)vr1 * S_ + nb0 + vc1);
    }

    f32x4 sc[2][4];
#pragma unroll
    for (int nt = 0; nt < 4; nt++) {
      f32x4 c0 = (f32x4){0.f, 0.f, 0.f, 0.f};
      f32x4 c1 = (f32x4){0.f, 0.f, 0.f, 0.f};
#pragma unroll
      for (int ks = 0; ks < 4; ks++) {
        short8 bfrag = *(const short8*)(Ks + (nt * 16 + rl) * KSTR + (ks * 4 + quad) * 8);
        c0 = __builtin_amdgcn_mfma_f32_16x16x32_bf16(qf[0][ks], bfrag, c0, 0, 0, 0);
        c1 = __builtin_amdgcn_mfma_f32_16x16x32_bf16(qf[1][ks], bfrag, c1, 0, 0, 0);
      }
      sc[0][nt] = c0; sc[1][nt] = c1;
    }
#pragma unroll
    for (int mt = 0; mt < 2; mt++) {
#pragma unroll
      for (int nt = 0; nt < 4; nt++)
#pragma unroll
        for (int r = 0; r < 4; r++) {
          int i_row = q0 + half * 32 + mt * 16 + quad * 4 + r;
          int j_col = kb0 + nt * 16 + rl;
          bool ok = (j_col <= i_row) && (i_row - j_col < WIN_);
          sc[mt][nt][r] = ok ? sc[mt][nt][r] * scale : -1e9f;
        }
#pragma unroll
      for (int r = 0; r < 4; r++) {
        float mx = fmaxf(fmaxf(sc[mt][0][r], sc[mt][1][r]),
                         fmaxf(sc[mt][2][r], sc[mt][3][r]));
#pragma unroll
        for (int m = 1; m < 16; m <<= 1) mx = fmaxf(mx, __shfl_xor(mx, m, 64));
        float newm = fmaxf(m_r[mt][r], mx);
        float alpha = __expf(m_r[mt][r] - newm);
        float p0 = __expf(sc[mt][0][r] - newm), p1 = __expf(sc[mt][1][r] - newm);
        float p2 = __expf(sc[mt][2][r] - newm), p3 = __expf(sc[mt][3][r] - newm);
        float rs = p0 + p1 + p2 + p3;
#pragma unroll
        for (int m = 1; m < 16; m <<= 1) rs += __shfl_xor(rs, m, 64);
        l_r[mt][r] = l_r[mt][r] * alpha + rs;
        m_r[mt][r] = newm;
#pragma unroll
        for (int j = 0; j < 8; j++) oacc[mt][j][r] *= alpha;
        int prow = (quad * 4 + r) * VSTR;
        unsigned short* pw = &Ps[wave][mt][prow];
        pw[0 * 16 + rl] = f2bf(p0);
        pw[1 * 16 + rl] = f2bf(p1);
        pw[2 * 16 + rl] = f2bf(p2);
        pw[3 * 16 + rl] = f2bf(p3);
      }
    }
#pragma unroll
    for (int ks2 = 0; ks2 < 2; ks2++) {
      short8 af0 = *(const short8*)(&Ps[wave][0][rl * VSTR + (ks2 * 4 + quad) * 8]);
      short8 af1 = *(const short8*)(&Ps[wave][1][rl * VSTR + (ks2 * 4 + quad) * 8]);
#pragma unroll
      for (int j = 0; j < 8; j++) {
        short8 bf2 = *(const short8*)(Vs + (j * 16 + rl) * VSTR + (ks2 * 4 + quad) * 8);
        oacc[0][j] = __builtin_amdgcn_mfma_f32_16x16x32_bf16(af0, bf2, oacc[0][j], 0, 0, 0);
        oacc[1][j] = __builtin_amdgcn_mfma_f32_16x16x32_bf16(af1, bf2, oacc[1][j], 0, 0, 0);
      }
    }
    if (kt < qt) {
      __syncthreads();
      *(short8*)(Ks + kr0 * KSTR + kc0) = k0v;
      *(short8*)(Ks + kr1 * KSTR + kc1) = k1v;
      *(short8*)(Vs + vr0 * VSTR + vc0) = v0v;
      *(short8*)(Vs + vr1 * VSTR + vc1) = v1v;
      __syncthreads();
    }
  }

#pragma unroll
  for (int mt = 0; mt < 2; mt++)
#pragma unroll
    for (int r = 0; r < 4; r++) {
      int s_idx = q0 + half * 32 + mt * 16 + quad * 4 + r;
      float invl = 1.0f / l_r[mt][r];
      long rowoff = (long)(b * S_ + s_idx);
      const unsigned short* grow = qkvg + rowoff * 5120 + 3072 + h * 128;
      unsigned short* orow = aout + rowoff * 2048 + h * 128;
#pragma unroll
      for (int j = 0; j < 8; j++) {
        int d = j * 16 + rl;
        float o = oacc[mt][j][r] * invl;
        float g = bf2f(grow[d]);
        o = o / (1.0f + __expf(-g));
        orow[d] = f2bf(o);
      }
    }
}

extern "C" void kernel_launch(void* const* d_in, const int* in_sizes, int n_in,
                              void* d_out, int out_size, void* d_ws, size_t ws_size,
                              hipStream_t stream) {
  (void)in_sizes; (void)n_in; (void)out_size; (void)ws_size;
  const float* hs   = (const float*)d_in[0];
  const float* cosb = (const float*)d_in[1];
  const float* sinb = (const float*)d_in[2];
  const float* Wq = (const float*)d_in[4];
  const float* Wk = (const float*)d_in[5];
  const float* Wv = (const float*)d_in[6];
  const float* Wo = (const float*)d_in[7];
  const float* Wg = (const float*)d_in[8];
  const float* qw = (const float*)d_in[9];
  const float* kw = (const float*)d_in[10];
  float* out = (float*)d_out;

  char* ws = (char*)d_ws;
  unsigned short* Xb   = (unsigned short*)ws; ws += (size_t)4096 * 2048 * 2;
  unsigned short* Wall = (unsigned short*)ws; ws += (size_t)5120 * 2048 * 2;
  unsigned short* Wob  = (unsigned short*)ws; ws += (size_t)2048 * 2048 * 2;
  unsigned short* qkvg = (unsigned short*)ws; ws += (size_t)4096 * 5120 * 2;
  unsigned short* qb   = (unsigned short*)ws; ws += (size_t)B_ * NH_ * S_ * D_ * 2;
  unsigned short* kbuf = (unsigned short*)ws; ws += (size_t)B_ * NKV_ * S_ * D_ * 2;
  unsigned short* vtb  = (unsigned short*)ws; ws += (size_t)B_ * NKV_ * S_ * D_ * 2;
  unsigned short* aout = (unsigned short*)ws; ws += (size_t)4096 * 2048 * 2;

  convert_all<<<(int)((CVT_TOTAL + 255) / 256), 256, 0, stream>>>(
      hs, Wq, Wk, Wv, Wg, Wo, Xb, Wall, Wob);
  gemm_bt<true><<<dim3(32, 40), 256, 0, stream>>>(Xb, Wall, (void*)qkvg, 4096, 5120, 2048);
  pack_norm_rope<<<20480, 256, 0, stream>>>(qkvg, cosb, sinb, qw, kw, qb, kbuf);
  v_transpose<<<256, 256, 0, stream>>>(qkvg, vtb);
  attn_kernel<<<256, 512, 0, stream>>>(qb, kbuf, vtb, qkvg, aout);
  gemm_bt<false><<<dim3(32, 16), 256, 0, stream>>>(aout, Wob, (void*)out, 4096, 2048, 2048);
}

// Round 6
// 396.387 us; speedup vs baseline: 1.3430x; 1.0622x over previous
//
#include <hip/hip_runtime.h>
#include <hip/hip_bf16.h>

#define B_    2
#define S_    2048
#define H_    2048
#define NH_   16
#define NKV_  4
#define D_    128
#define WIN_  1024

typedef __attribute__((ext_vector_type(8))) short short8;
typedef __attribute__((ext_vector_type(4))) float f32x4;

__device__ __forceinline__ void gl2lds16(const void* g, void* l) {
  __builtin_amdgcn_global_load_lds(
      (const __attribute__((address_space(1))) void*)g,
      (__attribute__((address_space(3))) void*)l, 16, 0, 0);
}

__device__ __forceinline__ unsigned short f2bf(float x) {
  union { float f; unsigned int u; } v; v.f = x;
  unsigned int r = v.u + 0x7fffu + ((v.u >> 16) & 1u);
  return (unsigned short)(r >> 16);
}
__device__ __forceinline__ float bf2f(unsigned short u) {
  union { unsigned int i; float f; } v; v.i = ((unsigned int)u) << 16; return v.f;
}

// ---------------- fused fp32 -> bf16 convert, all 6 tensors in one launch ----
// TOTAL = 5,767,168 float4 chunks = 22,528 blocks x 256.
#define CVT_TOTAL 5767168L
__global__ __launch_bounds__(256) void convert_all(
    const float* __restrict__ hs, const float* __restrict__ wq,
    const float* __restrict__ wk, const float* __restrict__ wv,
    const float* __restrict__ wg, const float* __restrict__ wo,
    unsigned short* __restrict__ xb, unsigned short* __restrict__ wall,
    unsigned short* __restrict__ wob) {
  long i = (long)blockIdx.x * 256 + threadIdx.x;
  if (i >= CVT_TOTAL) return;
  const float4* src; ushort4* dst;
  if (i < 2097152)      { src = (const float4*)hs + i;                         dst = (ushort4*)xb + i; }
  else if (i < 3145728) { long j = i - 2097152; src = (const float4*)wq + j;   dst = (ushort4*)wall + j; }
  else if (i < 3407872) { long j = i - 3145728; src = (const float4*)wk + j;   dst = (ushort4*)wall + 1048576 + j; }
  else if (i < 3670016) { long j = i - 3407872; src = (const float4*)wv + j;   dst = (ushort4*)wall + 1310720 + j; }
  else if (i < 4718592) { long j = i - 3670016; src = (const float4*)wg + j;   dst = (ushort4*)wall + 1572864 + j; }
  else                  { long j = i - 4718592; src = (const float4*)wo + j;   dst = (ushort4*)wob + j; }
  float4 v = *src;
  ushort4 o; o.x = f2bf(v.x); o.y = f2bf(v.y); o.z = f2bf(v.z); o.w = f2bf(v.w);
  *dst = o;
}

// ---------------- bf16 GEMM: C(MxN) = A(MxK) * B(NxK)^T ----------------
// 128x128 tile, BK=64 (32 K-iters: half the barrier drains of BK=32), 256 thr,
// global_load_lds(16B). Swizzle: physical 16B chunk pc of row r holds logical
// chunk pc^(r&7) (permutation within the 128B row -> global reads stay
// contiguous per row; gl2lds LDS writes stay contiguous). Fragment reads fetch
// physical (kk*4+quad)^(row&7) -> logical kk*4+quad; each 8-lane b128 phase
// covers bank bases {0,4,..,28} = all 32 banks, conflict-free.
template <bool OUT_BF16>
__global__ __launch_bounds__(256) void gemm_bt(
    const unsigned short* __restrict__ A,
    const unsigned short* __restrict__ Bm,
    void* __restrict__ Cv, int M, int N, int K)
{
  __shared__ unsigned short As[128 * 64];
  __shared__ unsigned short Bs[128 * 64];
  const int t = threadIdx.x;
  const int lane = t & 63, wave = t >> 6;
  const int quad = lane >> 4, rl = lane & 15;
  const int bm = blockIdx.x * 128, bn = blockIdx.y * 128;
  const int wm = (wave >> 1) * 64, wn = (wave & 1) * 64;
  const int ldsbase = (t & ~63) * 8;   // wave*512 shorts (1 KiB per wave-instr)

  f32x4 acc[4][4];
#pragma unroll
  for (int i = 0; i < 4; i++)
#pragma unroll
    for (int j = 0; j < 4; j++) acc[i][j] = (f32x4){0.f, 0.f, 0.f, 0.f};

  for (int k0 = 0; k0 < K; k0 += 64) {
#pragma unroll
    for (int i = 0; i < 4; i++) {
      int tt = i * 256 + t;                    // physical 16B-chunk id (0..1023)
      int row = tt >> 3;
      int lc = (tt & 7) ^ (row & 7);           // logical chunk to fetch
      gl2lds16(A + (long)(bm + row) * K + k0 + lc * 8, As + i * 2048 + ldsbase);
      gl2lds16(Bm + (long)(bn + row) * K + k0 + lc * 8, Bs + i * 2048 + ldsbase);
    }
    __syncthreads();
#pragma unroll
    for (int kk = 0; kk < 2; kk++) {
      short8 af[4], bfr[4];
#pragma unroll
      for (int i = 0; i < 4; i++) {
        int row = wm + i * 16 + rl;
        af[i] = *(const short8*)(As + row * 64 + (((kk * 4 + quad) ^ (row & 7)) * 8));
      }
#pragma unroll
      for (int j = 0; j < 4; j++) {
        int row = wn + j * 16 + rl;
        bfr[j] = *(const short8*)(Bs + row * 64 + (((kk * 4 + quad) ^ (row & 7)) * 8));
      }
#pragma unroll
      for (int i = 0; i < 4; i++)
#pragma unroll
        for (int j = 0; j < 4; j++)
          acc[i][j] = __builtin_amdgcn_mfma_f32_16x16x32_bf16(af[i], bfr[j], acc[i][j], 0, 0, 0);
    }
    __syncthreads();
  }
#pragma unroll
  for (int i = 0; i < 4; i++) {
    int row0 = bm + wm + i * 16 + quad * 4;
#pragma unroll
    for (int j = 0; j < 4; j++) {
      int col = bn + wn + j * 16 + rl;
#pragma unroll
      for (int r = 0; r < 4; r++) {
        if (OUT_BF16)
          ((unsigned short*)Cv)[(long)(row0 + r) * N + col] = f2bf(acc[i][j][r]);
        else
          ((float*)Cv)[(long)(row0 + r) * N + col] = acc[i][j][r];
      }
    }
  }
}

// ------- RMSNorm+RoPE pack (blocks 0..20479) + V transpose (blocks 20480+) ---
__global__ __launch_bounds__(256) void pack_and_transpose(
    const unsigned short* __restrict__ qkvg,
    const float* __restrict__ cosb, const float* __restrict__ sinb,
    const float* __restrict__ qw, const float* __restrict__ kw,
    unsigned short* __restrict__ qb, unsigned short* __restrict__ kb,
    unsigned short* __restrict__ vt)
{
  __shared__ unsigned short tile[64][136];
  int t = threadIdx.x;
  if (blockIdx.x >= 20480) {                   // ---- V transpose path ----
    int blk = blockIdx.x - 20480;
    int st = blk & 31, kv = (blk >> 5) & 3, b = blk >> 7;
    int s0 = st * 64;
#pragma unroll
    for (int i = 0; i < 4; i++) {
      int idx = i * 256 + t;
      int r = idx >> 4, c = (idx & 15) * 8;
      short8 v = *(const short8*)(qkvg + (long)(b * S_ + s0 + r) * 5120 + 2560 + kv * 128 + c);
      *(short8*)(&tile[r][c]) = v;
    }
    __syncthreads();
    long vo = (long)(b * NKV_ + kv) * 128;
#pragma unroll
    for (int i = 0; i < 8; i++) {
      int idx = i * 256 + t;
      int d = idx >> 4, sc = idx & 15;
      ushort4 o;
      o.x = tile[sc * 4 + 0][d]; o.y = tile[sc * 4 + 1][d];
      o.z = tile[sc * 4 + 2][d]; o.w = tile[sc * 4 + 3][d];
      *(ushort4*)(vt + (vo + d) * S_ + s0 + sc * 4) = o;
    }
    return;
  }
  // ---- RMSNorm + RoPE path ----
  int lane = t & 63, wave = t >> 6;
  long gw = (long)blockIdx.x * 4 + wave;
  int hu = (int)(gw % 20);
  long bs = gw / 20;
  int b = (int)(bs / S_);
  int s = (int)(bs % S_);
  const unsigned short* row = qkvg + bs * 5120;

  bool isq = hu < 16;
  const unsigned short* base = isq ? (row + hu * 128) : (row + 2048 + (hu - 16) * 128);
  float x1 = bf2f(base[lane]), x2 = bf2f(base[lane + 64]);
  float ss = x1 * x1 + x2 * x2;
#pragma unroll
  for (int m = 1; m < 64; m <<= 1) ss += __shfl_xor(ss, m, 64);
  float inv = rsqrtf(ss * (1.0f / 128.0f) + 1e-5f);
  const float* w = isq ? qw : kw;
  float n1 = x1 * inv * w[lane], n2 = x2 * inv * w[lane + 64];
  const float* cp = cosb + bs * 128;
  const float* sp = sinb + bs * 128;
  float o1 = n1 * cp[lane] - n2 * sp[lane];
  float o2 = n2 * cp[lane + 64] + n1 * sp[lane + 64];
  if (isq) {
    long o = ((long)(b * NH_ + hu) * S_ + s) * 128;
    qb[o + lane] = f2bf(o1); qb[o + lane + 64] = f2bf(o2);
  } else {
    long o = ((long)(b * NKV_ + (hu - 16)) * S_ + s) * 128;
    kb[o + lane] = f2bf(o1); kb[o + lane + 64] = f2bf(o2);
  }
}

// ---------------- flash attention: 512 blocks x 4 waves, GQA-shared K/V -----
// Block = (b, kv, qt, q-half): 4 waves = 4 heads, each wave does 32 q rows
// (2 mtiles). LDS 54.2 KB -> 2 independent blocks/CU (barrier overlap).
#define KSTR 136   // 128 + 8 shorts
#define VSTR 72    // 64 + 8 shorts
__global__ __launch_bounds__(256, 2) void attn_kernel(
    const unsigned short* __restrict__ qb,   // [B,NH,S,D]
    const unsigned short* __restrict__ kbuf, // [B,NKV,S,D]
    const unsigned short* __restrict__ vt,   // [B,NKV,D,S]
    const unsigned short* __restrict__ qkvg, // gate at col 3072+
    unsigned short* __restrict__ aout)       // [B,S,NH*D] bf16
{
  __shared__ unsigned short Ks[64 * KSTR];      // (key, d) padded
  __shared__ unsigned short Vs[128 * VSTR];     // (d, key) padded
  __shared__ unsigned short Ps[4][2][16 * VSTR];// per-wave, per-mtile P
  int t = threadIdx.x, lane = t & 63, wave = t >> 6;
  int quad = lane >> 4, rl = lane & 15;
  int blk = blockIdx.x;
  int qh = blk & 1;
  int qt = 31 - ((blk >> 1) & 31);           // heavy blocks dispatch first
  int kv = (blk >> 6) & 3, b = blk >> 8;
  int h = kv * 4 + wave;
  int q0 = qt * 64;

  const unsigned short* qhead = qb + (((long)(b * NH_ + h)) * S_) * 128;
  short8 qf[2][4];
#pragma unroll
  for (int mt = 0; mt < 2; mt++)
#pragma unroll
    for (int ks = 0; ks < 4; ks++)
      qf[mt][ks] = *(const short8*)(qhead +
          (long)(q0 + qh * 32 + mt * 16 + rl) * 128 + ks * 32 + quad * 8);

  f32x4 oacc[2][8];
#pragma unroll
  for (int mt = 0; mt < 2; mt++)
#pragma unroll
    for (int j = 0; j < 8; j++) oacc[mt][j] = (f32x4){0.f, 0.f, 0.f, 0.f};
  float m_r[2][4], l_r[2][4];
#pragma unroll
  for (int mt = 0; mt < 2; mt++)
#pragma unroll
    for (int r = 0; r < 4; r++) { m_r[mt][r] = -1e9f; l_r[mt][r] = 0.f; }

  const unsigned short* kbase_p = kbuf + ((long)(b * NKV_ + kv)) * S_ * 128;
  const unsigned short* vbase_p = vt + ((long)(b * NKV_ + kv)) * 128 * S_;
  int t_lo = qt - 16; if (t_lo < 0) t_lo = 0;

  // staging indices: K = 64x16 chunks, V = 128x8 chunks; 1024 each / 256 thr
  int kr[4], kc[4], vr[4], vc[4];
#pragma unroll
  for (int i = 0; i < 4; i++) {
    int idx = i * 256 + t;
    kr[i] = idx >> 4; kc[i] = (idx & 15) * 8;
    vr[i] = idx >> 3; vc[i] = (idx & 7) * 8;
  }

  {
    int kb0 = t_lo * 64;
    short8 kv0[4], vv0[4];
#pragma unroll
    for (int i = 0; i < 4; i++) {
      kv0[i] = *(const short8*)(kbase_p + (long)(kb0 + kr[i]) * 128 + kc[i]);
      vv0[i] = *(const short8*)(vbase_p + (long)vr[i] * S_ + kb0 + vc[i]);
    }
#pragma unroll
    for (int i = 0; i < 4; i++) {
      *(short8*)(Ks + kr[i] * KSTR + kc[i]) = kv0[i];
      *(short8*)(Vs + vr[i] * VSTR + vc[i]) = vv0[i];
    }
  }
  __syncthreads();

  const float scale = 0.08838834764831845f;  // 1/sqrt(128)
  for (int kt = t_lo; kt <= qt; ++kt) {
    int kb0 = kt * 64;
    short8 kpre[4], vpre[4];
    if (kt < qt) {
      int nb0 = kb0 + 64;
#pragma unroll
      for (int i = 0; i < 4; i++) {
        kpre[i] = *(const short8*)(kbase_p + (long)(nb0 + kr[i]) * 128 + kc[i]);
        vpre[i] = *(const short8*)(vbase_p + (long)vr[i] * S_ + nb0 + vc[i]);
      }
    }

    f32x4 sc[2][4];
#pragma unroll
    for (int nt = 0; nt < 4; nt++) {
      f32x4 c0 = (f32x4){0.f, 0.f, 0.f, 0.f};
      f32x4 c1 = (f32x4){0.f, 0.f, 0.f, 0.f};
#pragma unroll
      for (int ks = 0; ks < 4; ks++) {
        short8 bfrag = *(const short8*)(Ks + (nt * 16 + rl) * KSTR + (ks * 4 + quad) * 8);
        c0 = __builtin_amdgcn_mfma_f32_16x16x32_bf16(qf[0][ks], bfrag, c0, 0, 0, 0);
        c1 = __builtin_amdgcn_mfma_f32_16x16x32_bf16(qf[1][ks], bfrag, c1, 0, 0, 0);
      }
      sc[0][nt] = c0; sc[1][nt] = c1;
    }
#pragma unroll
    for (int mt = 0; mt < 2; mt++) {
#pragma unroll
      for (int nt = 0; nt < 4; nt++)
#pragma unroll
        for (int r = 0; r < 4; r++) {
          int i_row = q0 + qh * 32 + mt * 16 + quad * 4 + r;
          int j_col = kb0 + nt * 16 + rl;
          bool ok = (j_col <= i_row) && (i_row - j_col < WIN_);
          sc[mt][nt][r] = ok ? sc[mt][nt][r] * scale : -1e9f;
        }
#pragma unroll
      for (int r = 0; r < 4; r++) {
        float mx = fmaxf(fmaxf(sc[mt][0][r], sc[mt][1][r]),
                         fmaxf(sc[mt][2][r], sc[mt][3][r]));
#pragma unroll
        for (int m = 1; m < 16; m <<= 1) mx = fmaxf(mx, __shfl_xor(mx, m, 64));
        float newm = fmaxf(m_r[mt][r], mx);
        float alpha = __expf(m_r[mt][r] - newm);
        float p0 = __expf(sc[mt][0][r] - newm), p1 = __expf(sc[mt][1][r] - newm);
        float p2 = __expf(sc[mt][2][r] - newm), p3 = __expf(sc[mt][3][r] - newm);
        float rs = p0 + p1 + p2 + p3;
#pragma unroll
        for (int m = 1; m < 16; m <<= 1) rs += __shfl_xor(rs, m, 64);
        l_r[mt][r] = l_r[mt][r] * alpha + rs;
        m_r[mt][r] = newm;
#pragma unroll
        for (int j = 0; j < 8; j++) oacc[mt][j][r] *= alpha;
        int prow = (quad * 4 + r) * VSTR;
        unsigned short* pw = &Ps[wave][mt][prow];
        pw[0 * 16 + rl] = f2bf(p0);
        pw[1 * 16 + rl] = f2bf(p1);
        pw[2 * 16 + rl] = f2bf(p2);
        pw[3 * 16 + rl] = f2bf(p3);
      }
    }
#pragma unroll
    for (int ks2 = 0; ks2 < 2; ks2++) {
      short8 af0 = *(const short8*)(&Ps[wave][0][rl * VSTR + (ks2 * 4 + quad) * 8]);
      short8 af1 = *(const short8*)(&Ps[wave][1][rl * VSTR + (ks2 * 4 + quad) * 8]);
#pragma unroll
      for (int j = 0; j < 8; j++) {
        short8 bf2 = *(const short8*)(Vs + (j * 16 + rl) * VSTR + (ks2 * 4 + quad) * 8);
        oacc[0][j] = __builtin_amdgcn_mfma_f32_16x16x32_bf16(af0, bf2, oacc[0][j], 0, 0, 0);
        oacc[1][j] = __builtin_amdgcn_mfma_f32_16x16x32_bf16(af1, bf2, oacc[1][j], 0, 0, 0);
      }
    }
    if (kt < qt) {
      __syncthreads();
#pragma unroll
      for (int i = 0; i < 4; i++) {
        *(short8*)(Ks + kr[i] * KSTR + kc[i]) = kpre[i];
        *(short8*)(Vs + vr[i] * VSTR + vc[i]) = vpre[i];
      }
      __syncthreads();
    }
  }

#pragma unroll
  for (int mt = 0; mt < 2; mt++)
#pragma unroll
    for (int r = 0; r < 4; r++) {
      int s_idx = q0 + qh * 32 + mt * 16 + quad * 4 + r;
      float invl = 1.0f / l_r[mt][r];
      long rowoff = (long)(b * S_ + s_idx);
      const unsigned short* grow = qkvg + rowoff * 5120 + 3072 + h * 128;
      unsigned short* orow = aout + rowoff * 2048 + h * 128;
#pragma unroll
      for (int j = 0; j < 8; j++) {
        int d = j * 16 + rl;
        float o = oacc[mt][j][r] * invl;
        float g = bf2f(grow[d]);
        o = o / (1.0f + __expf(-g));
        orow[d] = f2bf(o);
      }
    }
}

extern "C" void kernel_launch(void* const* d_in, const int* in_sizes, int n_in,
                              void* d_out, int out_size, void* d_ws, size_t ws_size,
                              hipStream_t stream) {
  (void)in_sizes; (void)n_in; (void)out_size; (void)ws_size;
  const float* hs   = (const float*)d_in[0];
  const float* cosb = (const float*)d_in[1];
  const float* sinb = (const float*)d_in[2];
  const float* Wq = (const float*)d_in[4];
  const float* Wk = (const float*)d_in[5];
  const float* Wv = (const float*)d_in[6];
  const float* Wo = (const float*)d_in[7];
  const float* Wg = (const float*)d_in[8];
  const float* qw = (const float*)d_in[9];
  const float* kw = (const float*)d_in[10];
  float* out = (float*)d_out;

  char* ws = (char*)d_ws;
  unsigned short* Xb   = (unsigned short*)ws; ws += (size_t)4096 * 2048 * 2;
  unsigned short* Wall = (unsigned short*)ws; ws += (size_t)5120 * 2048 * 2;
  unsigned short* Wob  = (unsigned short*)ws; ws += (size_t)2048 * 2048 * 2;
  unsigned short* qkvg = (unsigned short*)ws; ws += (size_t)4096 * 5120 * 2;
  unsigned short* qb   = (unsigned short*)ws; ws += (size_t)B_ * NH_ * S_ * D_ * 2;
  unsigned short* kbuf = (unsigned short*)ws; ws += (size_t)B_ * NKV_ * S_ * D_ * 2;
  unsigned short* vtb  = (unsigned short*)ws; ws += (size_t)B_ * NKV_ * S_ * D_ * 2;
  unsigned short* aout = (unsigned short*)ws; ws += (size_t)4096 * 2048 * 2;

  convert_all<<<(int)((CVT_TOTAL + 255) / 256), 256, 0, stream>>>(
      hs, Wq, Wk, Wv, Wg, Wo, Xb, Wall, Wob);
  gemm_bt<true><<<dim3(32, 40), 256, 0, stream>>>(Xb, Wall, (void*)qkvg, 4096, 5120, 2048);
  pack_and_transpose<<<20736, 256, 0, stream>>>(qkvg, cosb, sinb, qw, kw, qb, kbuf, vtb);
  attn_kernel<<<512, 256, 0, stream>>>(qb, kbuf, vtb, qkvg, aout);
  gemm_bt<false><<<dim3(32, 16), 256, 0, stream>>>(aout, Wob, (void*)out, 4096, 2048, 2048);
}